// Round 1
// baseline (1156.432 us; speedup 1.0000x reference)
//
#include <hip/hip_runtime.h>
#include <hip/hip_bf16.h>

#define N_NODES  100000
#define N_EDGES  1200000
#define N_GRAPHS 256
#define HID      64

// ---------------------------------------------------------------------------
// degree count over dst (real edges only; self-loop handled as +1 later)
__global__ void k_count(const int* __restrict__ dst, int* __restrict__ indeg, int e) {
    int i = blockIdx.x * blockDim.x + threadIdx.x;
    if (i < e) atomicAdd(&indeg[dst[i]], 1);
}

// single-block scan: exclusive prefix of indeg -> row_off[0..n], row_off[n]=total
__global__ void k_scan(const int* __restrict__ indeg, int* __restrict__ row_off, int n) {
    __shared__ int part[1024];
    const int tid = threadIdx.x;
    const int CH  = (n + 1023) / 1024;
    int begin = tid * CH; if (begin > n) begin = n;
    int end   = begin + CH; if (end > n) end = n;
    int s = 0;
    for (int i = begin; i < end; ++i) s += indeg[i];
    part[tid] = s;
    __syncthreads();
    // Hillis-Steele inclusive scan
    for (int off = 1; off < 1024; off <<= 1) {
        int v = (tid >= off) ? part[tid - off] : 0;
        __syncthreads();
        part[tid] += v;
        __syncthreads();
    }
    int excl = (tid == 0) ? 0 : part[tid - 1];
    for (int i = begin; i < end; ++i) { row_off[i] = excl; excl += indeg[i]; }
    if (tid == 1023) row_off[n] = part[1023];
}

__global__ void k_dinv(const int* __restrict__ indeg, float* __restrict__ dinv, int n) {
    int i = blockIdx.x * blockDim.x + threadIdx.x;
    if (i < n) dinv[i] = rsqrtf((float)indeg[i] + 1.0f);   // +1 self-loop
}

__global__ void k_fill(const int* __restrict__ src, const int* __restrict__ dst,
                       const int* __restrict__ row_off, int* __restrict__ cursor,
                       int* __restrict__ csr_src, int e) {
    int i = blockIdx.x * blockDim.x + threadIdx.x;
    if (i < e) {
        int d   = dst[i];
        int pos = row_off[d] + atomicAdd(&cursor[d], 1);
        csr_src[pos] = src[i];
    }
}

// ---------------------------------------------------------------------------
// g[n][j] = dinv[n] * sum_k in[n][k] * W[k][j]   (4 nodes per 256-thread block)
template <int K>
__global__ void k_mm(const float* __restrict__ in, const float* __restrict__ W,
                     const float* __restrict__ dinv, float* __restrict__ g, int n) {
    __shared__ float Wl[K * 64];
    __shared__ float rowb[4][64];
    const int tid  = threadIdx.x;
    for (int i = tid; i < K * 64; i += 256) Wl[i] = W[i];
    __syncthreads();
    const int w    = tid >> 6;
    const int lane = tid & 63;
    const int node = blockIdx.x * 4 + w;
    if (node >= n) return;
    const float* row = in + (size_t)node * K;
    if (lane < K) rowb[w][lane] = row[lane];     // wave-local, no barrier needed
    float acc = 0.f;
#pragma unroll
    for (int k = 0; k < K; ++k) acc = fmaf(rowb[w][k], Wl[k * 64 + lane], acc);
    g[(size_t)node * 64 + lane] = dinv[node] * acc;
}

// out[n][j] = relu(b[j] + dinv[n] * (g[n][j] + sum_{e: dst=n} g[src_e][j]))
__global__ void k_agg(const float* __restrict__ g, const int* __restrict__ row_off,
                      const int* __restrict__ csr_src, const float* __restrict__ dinv,
                      const float* __restrict__ b, float* __restrict__ out, int n) {
    const int tid  = threadIdx.x;
    const int node = blockIdx.x * 4 + (tid >> 6);
    const int lane = tid & 63;
    if (node >= n) return;
    float acc = g[(size_t)node * 64 + lane];     // self-loop term
    const int s0 = row_off[node], s1 = row_off[node + 1];
    for (int p = s0; p < s1; ++p) {
        int s = csr_src[p];
        acc += g[(size_t)s * 64 + lane];
    }
    float v = fmaf(dinv[node], acc, b[lane]);
    out[(size_t)node * 64 + lane] = fmaxf(v, 0.f);
}

// ---------------------------------------------------------------------------
__global__ void k_pool_count(const int* __restrict__ batch, int* __restrict__ cnt, int n) {
    int i = blockIdx.x * blockDim.x + threadIdx.x;
    if (i < n) atomicAdd(&cnt[batch[i]], 1);
}

__global__ void k_pool_sum(const float* __restrict__ h, const int* __restrict__ batch,
                           float* __restrict__ out, int n) {
    int idx  = blockIdx.x * blockDim.x + threadIdx.x;
    int node = idx >> 6, lane = idx & 63;
    if (node < n) atomicAdd(&out[batch[node] * 64 + lane], h[(size_t)node * 64 + lane]);
}

__global__ void k_pool_div(float* __restrict__ out, const int* __restrict__ cnt) {
    int i = blockIdx.x * blockDim.x + threadIdx.x;
    if (i < N_GRAPHS * 64) {
        float c = (float)cnt[i >> 6];
        out[i] /= fmaxf(c, 1.0f);
    }
}

// ---------------------------------------------------------------------------
static inline size_t al256(size_t x) { return (x + 255) & ~(size_t)255; }

extern "C" void kernel_launch(void* const* d_in, const int* in_sizes, int n_in,
                              void* d_out, int out_size, void* d_ws, size_t ws_size,
                              hipStream_t stream) {
    const float* x     = (const float*)d_in[0];
    const int*   eidx  = (const int*)d_in[1];     // [2, E] row-major: src then dst
    const int*   batch = (const int*)d_in[2];
    const float* W1 = (const float*)d_in[3];  const float* b1 = (const float*)d_in[4];
    const float* W2 = (const float*)d_in[5];  const float* b2 = (const float*)d_in[6];
    const float* W3 = (const float*)d_in[7];  const float* b3 = (const float*)d_in[8];
    const float* W4 = (const float*)d_in[9];  const float* b4 = (const float*)d_in[10];
    float* out = (float*)d_out;

    const int* src = eidx;
    const int* dst = eidx + N_EDGES;

    // workspace carve-up
    char* p = (char*)d_ws;
    size_t off = 0;
    int*   indeg   = (int*)(p + off);  off = al256(off + sizeof(int)   * N_NODES);
    int*   row_off = (int*)(p + off);  off = al256(off + sizeof(int)   * (N_NODES + 1));
    int*   cursor  = (int*)(p + off);  off = al256(off + sizeof(int)   * N_NODES);
    int*   cnt     = (int*)(p + off);  off = al256(off + sizeof(int)   * N_GRAPHS);
    float* dinv    = (float*)(p + off);off = al256(off + sizeof(float) * N_NODES);
    int*   csr_src = (int*)(p + off);  off = al256(off + sizeof(int)   * N_EDGES);
    float* B0      = (float*)(p + off);off = al256(off + sizeof(float) * (size_t)N_NODES * 64);
    float* B1      = (float*)(p + off);off = al256(off + sizeof(float) * (size_t)N_NODES * 64);
    (void)ws_size; (void)n_in; (void)in_sizes; (void)out_size;

    // zero the counters and the output accumulator
    hipMemsetAsync(indeg,  0, sizeof(int) * N_NODES, stream);
    hipMemsetAsync(cursor, 0, sizeof(int) * N_NODES, stream);
    hipMemsetAsync(cnt,    0, sizeof(int) * N_GRAPHS, stream);
    hipMemsetAsync(out,    0, sizeof(float) * N_GRAPHS * 64, stream);

    const int TB = 256;
    const int egrid = (N_EDGES + TB - 1) / TB;
    const int ngrid = (N_NODES + TB - 1) / TB;
    const int ngrid4 = (N_NODES + 3) / 4;          // 4 nodes per block (wave per node)

    k_count<<<egrid, TB, 0, stream>>>(dst, indeg, N_EDGES);
    k_scan <<<1, 1024, 0, stream>>>(indeg, row_off, N_NODES);
    k_dinv <<<ngrid, TB, 0, stream>>>(indeg, dinv, N_NODES);
    k_fill <<<egrid, TB, 0, stream>>>(src, dst, row_off, cursor, csr_src, N_EDGES);

    // layer 1: x(15) -> B0 -> B1
    k_mm<15><<<ngrid4, TB, 0, stream>>>(x,  W1, dinv, B0, N_NODES);
    k_agg    <<<ngrid4, TB, 0, stream>>>(B0, row_off, csr_src, dinv, b1, B1, N_NODES);
    // layer 2
    k_mm<64><<<ngrid4, TB, 0, stream>>>(B1, W2, dinv, B0, N_NODES);
    k_agg    <<<ngrid4, TB, 0, stream>>>(B0, row_off, csr_src, dinv, b2, B1, N_NODES);
    // layer 3
    k_mm<64><<<ngrid4, TB, 0, stream>>>(B1, W3, dinv, B0, N_NODES);
    k_agg    <<<ngrid4, TB, 0, stream>>>(B0, row_off, csr_src, dinv, b3, B1, N_NODES);
    // layer 4
    k_mm<64><<<ngrid4, TB, 0, stream>>>(B1, W4, dinv, B0, N_NODES);
    k_agg    <<<ngrid4, TB, 0, stream>>>(B0, row_off, csr_src, dinv, b4, B1, N_NODES);

    // mean pool
    k_pool_count<<<ngrid, TB, 0, stream>>>(batch, cnt, N_NODES);
    k_pool_sum  <<<(N_NODES * 64 + TB - 1) / TB, TB, 0, stream>>>(B1, batch, out, N_NODES);
    k_pool_div  <<<(N_GRAPHS * 64 + TB - 1) / TB, TB, 0, stream>>>(out, cnt);
}

// Round 2
// 406.039 us; speedup vs baseline: 2.8481x; 2.8481x over previous
//
#include <hip/hip_runtime.h>
#include <hip/hip_bf16.h>

#define NN 100000
#define NE 1200000
#define NG 256
#define NBLK 391   // ceil(NN/256)

// ---------------------------------------------------------------------------
__global__ void k_count(const int* __restrict__ dst, int* __restrict__ indeg) {
    int i = blockIdx.x * 256 + threadIdx.x;
    if (i < NE) atomicAdd(&indeg[dst[i]], 1);
}

// 3-kernel exclusive scan of indeg -> row_off (row_off[NN] = total)
__global__ void k_blkred(const int* __restrict__ indeg, int* __restrict__ part) {
    __shared__ int s[4];
    int i = blockIdx.x * 256 + threadIdx.x;
    int v = (i < NN) ? indeg[i] : 0;
    for (int o = 32; o; o >>= 1) v += __shfl_down(v, o);
    if ((threadIdx.x & 63) == 0) s[threadIdx.x >> 6] = v;
    __syncthreads();
    if (threadIdx.x == 0) part[blockIdx.x] = s[0] + s[1] + s[2] + s[3];
}

__global__ void k_scanpart(const int* __restrict__ part, int* __restrict__ partoff,
                           int* __restrict__ row_off) {
    __shared__ int s[512];
    int t = threadIdx.x;
    int v = (t < NBLK) ? part[t] : 0;
    s[t] = v;
    __syncthreads();
    for (int o = 1; o < 512; o <<= 1) {
        int u = (t >= o) ? s[t - o] : 0;
        __syncthreads();
        s[t] += u;
        __syncthreads();
    }
    if (t < NBLK) partoff[t] = s[t] - v;      // exclusive
    if (t == 511) row_off[NN] = s[511];
}

__global__ void k_scatter(const int* __restrict__ indeg, const int* __restrict__ partoff,
                          int* __restrict__ row_off) {
    __shared__ int s[256];
    int t = threadIdx.x;
    int i = blockIdx.x * 256 + t;
    int v = (i < NN) ? indeg[i] : 0;
    s[t] = v;
    __syncthreads();
    for (int o = 1; o < 256; o <<= 1) {
        int u = (t >= o) ? s[t - o] : 0;
        __syncthreads();
        s[t] += u;
        __syncthreads();
    }
    if (i < NN) row_off[i] = partoff[blockIdx.x] + s[t] - v;
}

__global__ void k_dinv(const int* __restrict__ indeg, float* __restrict__ dinv) {
    int i = blockIdx.x * 256 + threadIdx.x;
    if (i < NN) dinv[i] = rsqrtf((float)indeg[i] + 1.0f);   // +1 self-loop
}

__global__ void k_fill(const int* __restrict__ src, const int* __restrict__ dst,
                       const int* __restrict__ row_off, int* __restrict__ cursor,
                       int* __restrict__ csr_src) {
    int i = blockIdx.x * 256 + threadIdx.x;
    if (i < NE) {
        int d = dst[i];
        int pos = row_off[d] + atomicAdd(&cursor[d], 1);
        csr_src[pos] = src[i];
    }
}

// xs[n][k] = dinv[n]*x[n][k] for k<15, 0 for k==15  (padded to 16)
__global__ void k_pad(const float* __restrict__ x, const float* __restrict__ dinv,
                      float* __restrict__ xs) {
    int i = blockIdx.x * 256 + threadIdx.x;
    if (i < NN * 16) {
        int n = i >> 4, k = i & 15;
        xs[i] = (k < 15) ? dinv[n] * x[n * 15 + k] : 0.f;
    }
}

// ---------------------------------------------------------------------------
// a[n] = dinv[n] * ( sum_{e:dst=n} xs[src_e] + xs[n] )     DIM-dim rows
template <int DIM>
__global__ void k_agg(const float* __restrict__ xs, const int* __restrict__ row_off,
                      const int* __restrict__ csr, const float* __restrict__ dinv,
                      float* __restrict__ out) {
    constexpr int LPN = DIM / 4;          // lanes per node
    constexpr int NPB = 256 / LPN;        // nodes per block
    const int t = threadIdx.x;
    const int node = blockIdx.x * NPB + t / LPN;
    const int c4 = t % LPN;
    if (node >= NN) return;
    const float4* base = (const float4*)xs;
    float4 acc = base[(size_t)node * LPN + c4];          // self-loop term
    int p = row_off[node], e = row_off[node + 1];
    for (; p + 1 < e; p += 2) {
        int sA = csr[p], sB = csr[p + 1];
        float4 a = base[(size_t)sA * LPN + c4];
        float4 b = base[(size_t)sB * LPN + c4];
        acc.x += a.x + b.x; acc.y += a.y + b.y;
        acc.z += a.z + b.z; acc.w += a.w + b.w;
    }
    if (p < e) {
        float4 a = base[(size_t)csr[p] * LPN + c4];
        acc.x += a.x; acc.y += a.y; acc.z += a.z; acc.w += a.w;
    }
    float dv = dinv[node];
    float4 r; r.x = dv * acc.x; r.y = dv * acc.y; r.z = dv * acc.z; r.w = dv * acc.w;
    ((float4*)out)[(size_t)node * LPN + c4] = r;
}

// ---------------------------------------------------------------------------
// h = relu(a @ W + b);  out = LAST ? h : dinv*h    (16 nodes / 256-thr block)
template <int KD, int KROWS, bool LAST>
__global__ void k_mm(const float* __restrict__ a, const float* __restrict__ W,
                     const float* __restrict__ bias, const float* __restrict__ dinv,
                     float* __restrict__ out) {
    __shared__ float4 Wl[KD][16];         // KD x 64 floats
    __shared__ float  al[16][KD + 4];     // +4 pad: conflict-free, float4-aligned
    const int t = threadIdx.x;
    for (int i = t; i < KD * 16; i += 256) {
        int k = i / 16, c = i % 16;
        float4 w;
        if (k < KROWS) w = ((const float4*)W)[k * 16 + c];
        else { w.x = w.y = w.z = w.w = 0.f; }
        Wl[k][c] = w;
    }
    const int nodeBase = blockIdx.x * 16;
    for (int i = t; i < 16 * (KD / 4); i += 256) {
        int r = i / (KD / 4), c4 = i % (KD / 4);
        int n = nodeBase + r;
        float4 v;
        if (n < NN) v = ((const float4*)a)[(size_t)n * (KD / 4) + c4];
        else { v.x = v.y = v.z = v.w = 0.f; }
        ((float4*)&al[r][0])[c4] = v;
    }
    __syncthreads();
    const int nl = t >> 4;
    const int c  = t & 15;
    const int node = nodeBase + nl;
    if (node >= NN) return;
    float4 acc = ((const float4*)bias)[c];
#pragma unroll
    for (int k = 0; k < KD; ++k) {
        float av = al[nl][k];
        float4 w = Wl[k][c];
        acc.x = fmaf(av, w.x, acc.x);
        acc.y = fmaf(av, w.y, acc.y);
        acc.z = fmaf(av, w.z, acc.z);
        acc.w = fmaf(av, w.w, acc.w);
    }
    acc.x = fmaxf(acc.x, 0.f); acc.y = fmaxf(acc.y, 0.f);
    acc.z = fmaxf(acc.z, 0.f); acc.w = fmaxf(acc.w, 0.f);
    if (!LAST) {
        float dv = dinv[node];
        acc.x *= dv; acc.y *= dv; acc.z *= dv; acc.w *= dv;
    }
    ((float4*)out)[(size_t)node * 16 + c] = acc;
}

// ---------------------------------------------------------------------------
// batch is sorted: per-graph start offsets, then segment mean (no atomics)
__global__ void k_bounds(const int* __restrict__ batch, int* __restrict__ gstart) {
    int i = blockIdx.x * 256 + threadIdx.x;
    if (i >= NN) return;
    int b = batch[i];
    if (i == 0) {
        for (int g = 0; g <= b; ++g) gstart[g] = 0;
    } else {
        int bp = batch[i - 1];
        for (int g = bp + 1; g <= b; ++g) gstart[g] = i;
    }
    if (i == NN - 1) {
        for (int g = b + 1; g <= NG; ++g) gstart[g] = NN;
    }
}

__global__ void k_pool(const float* __restrict__ h, const int* __restrict__ gstart,
                       float* __restrict__ out) {
    __shared__ float s[4][64];
    int g = blockIdx.x;
    int t = threadIdx.x, lane = t & 63, w = t >> 6;
    int r0 = gstart[g], r1 = gstart[g + 1];
    float acc = 0.f;
    for (int r = r0 + w; r < r1; r += 4) acc += h[(size_t)r * 64 + lane];
    s[w][lane] = acc;
    __syncthreads();
    if (t < 64) {
        float v = s[0][t] + s[1][t] + s[2][t] + s[3][t];
        float c = (float)(r1 - r0);
        out[g * 64 + t] = v / fmaxf(c, 1.f);
    }
}

// ---------------------------------------------------------------------------
static inline size_t al256(size_t x) { return (x + 255) & ~(size_t)255; }

extern "C" void kernel_launch(void* const* d_in, const int* in_sizes, int n_in,
                              void* d_out, int out_size, void* d_ws, size_t ws_size,
                              hipStream_t stream) {
    const float* x     = (const float*)d_in[0];
    const int*   eidx  = (const int*)d_in[1];
    const int*   batch = (const int*)d_in[2];
    const float* W1 = (const float*)d_in[3];  const float* b1 = (const float*)d_in[4];
    const float* W2 = (const float*)d_in[5];  const float* b2 = (const float*)d_in[6];
    const float* W3 = (const float*)d_in[7];  const float* b3 = (const float*)d_in[8];
    const float* W4 = (const float*)d_in[9];  const float* b4 = (const float*)d_in[10];
    float* out = (float*)d_out;
    (void)in_sizes; (void)n_in; (void)out_size; (void)ws_size;

    const int* src = eidx;
    const int* dst = eidx + NE;

    char* p = (char*)d_ws;
    size_t off = 0;
    int*   indeg   = (int*)(p + off);   off = al256(off + sizeof(int) * NN);
    int*   row_off = (int*)(p + off);   off = al256(off + sizeof(int) * (NN + 1));
    int*   cursor  = (int*)(p + off);   off = al256(off + sizeof(int) * NN);
    int*   part    = (int*)(p + off);   off = al256(off + sizeof(int) * 512);
    int*   partoff = (int*)(p + off);   off = al256(off + sizeof(int) * 512);
    int*   gstart  = (int*)(p + off);   off = al256(off + sizeof(int) * (NG + 1));
    float* dinv    = (float*)(p + off); off = al256(off + sizeof(float) * NN);
    int*   csr     = (int*)(p + off);   off = al256(off + sizeof(int) * NE);
    float* Ba      = (float*)(p + off); off = al256(off + sizeof(float) * (size_t)NN * 64);
    float* Bh      = (float*)(p + off); off = al256(off + sizeof(float) * (size_t)NN * 64);
    float* xs      = Bh;                 // 16-dim padded input aliases Bh (dead before mm16 writes Bh)

    hipMemsetAsync(indeg,  0, sizeof(int) * NN, stream);
    hipMemsetAsync(cursor, 0, sizeof(int) * NN, stream);

    const int egrid = (NE + 255) / 256;

    k_count   <<<egrid, 256, 0, stream>>>(dst, indeg);
    k_blkred  <<<NBLK, 256, 0, stream>>>(indeg, part);
    k_scanpart<<<1, 512, 0, stream>>>(part, partoff, row_off);
    k_scatter <<<NBLK, 256, 0, stream>>>(indeg, partoff, row_off);
    k_dinv    <<<NBLK, 256, 0, stream>>>(indeg, dinv);
    k_fill    <<<egrid, 256, 0, stream>>>(src, dst, row_off, cursor, csr);
    k_pad     <<<(NN * 16 + 255) / 256, 256, 0, stream>>>(x, dinv, xs);

    // layer 1 (16-dim aggregate, then 16->64 matmul)
    k_agg<16> <<<(NN + 63) / 64, 256, 0, stream>>>(xs, row_off, csr, dinv, Ba);
    k_mm<16, 15, false><<<(NN + 15) / 16, 256, 0, stream>>>(Ba, W1, b1, dinv, Bh);
    // layer 2
    k_agg<64> <<<(NN + 15) / 16, 256, 0, stream>>>(Bh, row_off, csr, dinv, Ba);
    k_mm<64, 64, false><<<(NN + 15) / 16, 256, 0, stream>>>(Ba, W2, b2, dinv, Bh);
    // layer 3
    k_agg<64> <<<(NN + 15) / 16, 256, 0, stream>>>(Bh, row_off, csr, dinv, Ba);
    k_mm<64, 64, false><<<(NN + 15) / 16, 256, 0, stream>>>(Ba, W3, b3, dinv, Bh);
    // layer 4 (plain h out for pooling)
    k_agg<64> <<<(NN + 15) / 16, 256, 0, stream>>>(Bh, row_off, csr, dinv, Ba);
    k_mm<64, 64, true><<<(NN + 15) / 16, 256, 0, stream>>>(Ba, W4, b4, dinv, Bh);

    // mean pool (sorted batch -> segment sum, no atomics)
    k_bounds<<<NBLK, 256, 0, stream>>>(batch, gstart);
    k_pool  <<<NG, 256, 0, stream>>>(Bh, gstart, out);
}

// Round 3
// 294.883 us; speedup vs baseline: 3.9217x; 1.3769x over previous
//
#include <hip/hip_runtime.h>
#include <hip/hip_bf16.h>

#define NN 100000
#define NE 1200000
#define NG 256
#define NB 256          // dst buckets
#define BSZ 391         // nodes per bucket (ceil(NN/NB))
#define ECHUNK 4688     // edges per bucketize block (ceil(NE/256))
#define MAXB 6144       // max edges per bucket (mean 4692, sigma ~68)
#define NBLK 391        // ceil(NN/256)

// ---------------------------------------------------------------------------
// Phase 0: global bucket histogram (dst / BSZ)
__global__ void ph0_hist(const int* __restrict__ dst, int* __restrict__ bcount) {
    __shared__ int h[NB];
    const int t = threadIdx.x;
    h[t] = 0;
    __syncthreads();
    const int e0 = blockIdx.x * ECHUNK;
    const int cnt = min(ECHUNK, NE - e0);
    for (int i = t; i < cnt; i += 256)
        atomicAdd(&h[dst[e0 + i] / BSZ], 1);
    __syncthreads();
    atomicAdd(&bcount[t], h[t]);
}

// Phase 0b: scan bucket counts -> bbase[257], init gcur, set row_off[NN]
__global__ void ph_scan(const int* __restrict__ bcount, int* __restrict__ bbase,
                        int* __restrict__ gcur, int* __restrict__ row_off) {
    __shared__ int s[NB];
    const int t = threadIdx.x;
    int v = bcount[t];
    s[t] = v;
    __syncthreads();
    for (int off = 1; off < NB; off <<= 1) {
        int u = (t >= off) ? s[t - off] : 0;
        __syncthreads();
        s[t] += u;
        __syncthreads();
    }
    int base = s[t] - v;                  // exclusive
    bbase[t] = base;
    gcur[t] = base;
    if (t == NB - 1) { bbase[NB] = s[t]; row_off[NN] = NE; }
}

// Phase 1: bucketize edges into bucket-major packed array
__global__ void ph1_bucketize(const int* __restrict__ src, const int* __restrict__ dst,
                              int* __restrict__ gcur, unsigned* __restrict__ barray) {
    __shared__ int ldst[ECHUNK];
    __shared__ int lsrc[ECHUNK];
    __shared__ int hist[NB];
    __shared__ int lbase[NB];
    __shared__ int lcur[NB];
    const int t = threadIdx.x;
    const int e0 = blockIdx.x * ECHUNK;
    const int cnt = min(ECHUNK, NE - e0);
    hist[t] = 0;
    __syncthreads();
    for (int i = t; i < cnt; i += 256) {
        int d = dst[e0 + i], s = src[e0 + i];
        ldst[i] = d; lsrc[i] = s;
        atomicAdd(&hist[d / BSZ], 1);
    }
    __syncthreads();
    lbase[t] = atomicAdd(&gcur[t], hist[t]);   // reserve chunk in bucket t
    lcur[t] = 0;
    __syncthreads();
    for (int i = t; i < cnt; i += 256) {
        int d = ldst[i];
        int b = d / BSZ;
        int pos = lbase[b] + atomicAdd(&lcur[b], 1);
        barray[pos] = ((unsigned)(d - b * BSZ) << 17) | (unsigned)lsrc[i];
    }
}

// Phase 2: per-bucket CSR build, all global writes coalesced
__global__ void ph2_build(const unsigned* __restrict__ barray, const int* __restrict__ bbase,
                          int* __restrict__ row_off, float* __restrict__ dinv,
                          int* __restrict__ csr) {
    __shared__ unsigned estage[MAXB];
    __shared__ int lcsr[MAXB];
    __shared__ int s[512];
    __shared__ int cur[BSZ];
    const int t = threadIdx.x;
    const int b = blockIdx.x;
    const int ebase = bbase[b];
    const int cnt = bbase[b + 1] - ebase;
    const int nbase = b * BSZ;
    const int nnodes = min(BSZ, NN - nbase);
    s[t] = 0; s[t + 256] = 0;
    __syncthreads();
    for (int i = t; i < cnt; i += 256) {
        unsigned e = barray[ebase + i];
        estage[i] = e;
        atomicAdd(&s[e >> 17], 1);
    }
    __syncthreads();
    // inclusive scan of s[0..511] (each thread owns slots t and t+256)
    for (int off = 1; off < 512; off <<= 1) {
        int v1 = (t >= off) ? s[t - off] : 0;
        int v2 = s[t + 256 - off];
        __syncthreads();
        s[t] += v1; s[t + 256] += v2;
        __syncthreads();
    }
    for (int l = t; l < nnodes; l += 256) {
        int incl = s[l];
        int excl = l ? s[l - 1] : 0;
        row_off[nbase + l] = ebase + excl;
        dinv[nbase + l] = rsqrtf((float)(incl - excl) + 1.0f);  // +1 self-loop
        cur[l] = excl;
    }
    __syncthreads();
    for (int i = t; i < cnt; i += 256) {
        unsigned e = estage[i];
        int pos = atomicAdd(&cur[e >> 17], 1);
        lcsr[pos] = (int)(e & 0x1FFFFu);
    }
    __syncthreads();
    for (int i = t; i < cnt; i += 256)
        csr[ebase + i] = lcsr[i];
}

// ---------------------------------------------------------------------------
// xs[n][k] = dinv[n]*x[n][k] (k<15), 0 at k==15 (pad to 16)
__global__ void k_pad(const float* __restrict__ x, const float* __restrict__ dinv,
                      float* __restrict__ xs) {
    int i = blockIdx.x * 256 + threadIdx.x;
    if (i < NN * 16) {
        int n = i >> 4, k = i & 15;
        xs[i] = (k < 15) ? dinv[n] * x[n * 15 + k] : 0.f;
    }
}

// ---------------------------------------------------------------------------
// Layer 1 fused: 16-d gather -> 16x64 matmul. 64 nodes / 256-thread block.
__global__ void fused1(const float* __restrict__ xs, const int* __restrict__ row_off,
                       const int* __restrict__ csr, const float* __restrict__ dinv,
                       const float* __restrict__ W, const float* __restrict__ bias,
                       float* __restrict__ out) {
    __shared__ float4 Wl[16][16];        // 16 k-rows x 64 cols
    __shared__ float  al[64][20];        // row stride 80B (16B-aligned)
    const int t = threadIdx.x;
    if (t < 240) Wl[t >> 4][t & 15] = ((const float4*)W)[t];   // 15x64 = 240 float4
    if (t < 16) { float4 z = make_float4(0,0,0,0); Wl[15][t] = z; }
    const int nl = t >> 2, c4 = t & 3;
    const int node = blockIdx.x * 64 + nl;
    float4 acc = make_float4(0,0,0,0);
    float dv = 0.f;
    if (node < NN) {
        const float4* base = (const float4*)xs;
        acc = base[(size_t)node * 4 + c4];               // self-loop
        int p = row_off[node], e = row_off[node + 1];
        for (; p + 1 < e; p += 2) {
            int sA = csr[p], sB = csr[p + 1];
            float4 a = base[(size_t)sA * 4 + c4];
            float4 b = base[(size_t)sB * 4 + c4];
            acc.x += a.x + b.x; acc.y += a.y + b.y;
            acc.z += a.z + b.z; acc.w += a.w + b.w;
        }
        if (p < e) {
            float4 a = base[(size_t)csr[p] * 4 + c4];
            acc.x += a.x; acc.y += a.y; acc.z += a.z; acc.w += a.w;
        }
        dv = dinv[node];
        acc.x *= dv; acc.y *= dv; acc.z *= dv; acc.w *= dv;
    }
    ((float4*)&al[nl][0])[c4] = acc;
    __syncthreads();
    if (node >= NN) return;
    float4 o0 = ((const float4*)bias)[c4 * 4 + 0];
    float4 o1 = ((const float4*)bias)[c4 * 4 + 1];
    float4 o2 = ((const float4*)bias)[c4 * 4 + 2];
    float4 o3 = ((const float4*)bias)[c4 * 4 + 3];
#pragma unroll
    for (int k = 0; k < 16; ++k) {
        float a = al[nl][k];
        float4 w0 = Wl[k][c4 * 4 + 0];
        float4 w1 = Wl[k][c4 * 4 + 1];
        float4 w2 = Wl[k][c4 * 4 + 2];
        float4 w3 = Wl[k][c4 * 4 + 3];
        o0.x = fmaf(a, w0.x, o0.x); o0.y = fmaf(a, w0.y, o0.y); o0.z = fmaf(a, w0.z, o0.z); o0.w = fmaf(a, w0.w, o0.w);
        o1.x = fmaf(a, w1.x, o1.x); o1.y = fmaf(a, w1.y, o1.y); o1.z = fmaf(a, w1.z, o1.z); o1.w = fmaf(a, w1.w, o1.w);
        o2.x = fmaf(a, w2.x, o2.x); o2.y = fmaf(a, w2.y, o2.y); o2.z = fmaf(a, w2.z, o2.z); o2.w = fmaf(a, w2.w, o2.w);
        o3.x = fmaf(a, w3.x, o3.x); o3.y = fmaf(a, w3.y, o3.y); o3.z = fmaf(a, w3.z, o3.z); o3.w = fmaf(a, w3.w, o3.w);
    }
    o0.x = fmaxf(o0.x, 0.f); o0.y = fmaxf(o0.y, 0.f); o0.z = fmaxf(o0.z, 0.f); o0.w = fmaxf(o0.w, 0.f);
    o1.x = fmaxf(o1.x, 0.f); o1.y = fmaxf(o1.y, 0.f); o1.z = fmaxf(o1.z, 0.f); o1.w = fmaxf(o1.w, 0.f);
    o2.x = fmaxf(o2.x, 0.f); o2.y = fmaxf(o2.y, 0.f); o2.z = fmaxf(o2.z, 0.f); o2.w = fmaxf(o2.w, 0.f);
    o3.x = fmaxf(o3.x, 0.f); o3.y = fmaxf(o3.y, 0.f); o3.z = fmaxf(o3.z, 0.f); o3.w = fmaxf(o3.w, 0.f);
    o0.x *= dv; o0.y *= dv; o0.z *= dv; o0.w *= dv;
    o1.x *= dv; o1.y *= dv; o1.z *= dv; o1.w *= dv;
    o2.x *= dv; o2.y *= dv; o2.z *= dv; o2.w *= dv;
    o3.x *= dv; o3.y *= dv; o3.z *= dv; o3.w *= dv;
    float4* ob = (float4*)out + (size_t)node * 16 + c4 * 4;
    ob[0] = o0; ob[1] = o1; ob[2] = o2; ob[3] = o3;
}

// ---------------------------------------------------------------------------
// Layers 2..4 fused: 64-d gather -> 64x64 matmul. 16 nodes / 256-thread block.
template <bool LAST>
__global__ void fused64(const float* __restrict__ g, const int* __restrict__ row_off,
                        const int* __restrict__ csr, const float* __restrict__ dinv,
                        const float* __restrict__ W, const float* __restrict__ bias,
                        float* __restrict__ out) {
    __shared__ float4 Wl[64][16];        // 64 k-rows x 64 cols (16 KB)
    __shared__ float  al[16][68];        // row stride 272B (16B-aligned)
    const int t = threadIdx.x;
    for (int i = t; i < 1024; i += 256)
        Wl[i >> 4][i & 15] = ((const float4*)W)[i];
    const int nl = t >> 4, c4 = t & 15;
    const int node = blockIdx.x * 16 + nl;
    float4 acc = make_float4(0,0,0,0);
    float dv = 0.f;
    if (node < NN) {
        const float4* base = (const float4*)g;
        acc = base[(size_t)node * 16 + c4];              // self-loop
        int p = row_off[node], e = row_off[node + 1];
        for (; p + 1 < e; p += 2) {
            int sA = csr[p], sB = csr[p + 1];
            float4 a = base[(size_t)sA * 16 + c4];
            float4 b = base[(size_t)sB * 16 + c4];
            acc.x += a.x + b.x; acc.y += a.y + b.y;
            acc.z += a.z + b.z; acc.w += a.w + b.w;
        }
        if (p < e) {
            float4 a = base[(size_t)csr[p] * 16 + c4];
            acc.x += a.x; acc.y += a.y; acc.z += a.z; acc.w += a.w;
        }
        dv = dinv[node];
        acc.x *= dv; acc.y *= dv; acc.z *= dv; acc.w *= dv;
    }
    ((float4*)&al[nl][0])[c4] = acc;
    __syncthreads();
    if (node >= NN) return;
    float4 o = ((const float4*)bias)[c4];
#pragma unroll
    for (int k = 0; k < 64; ++k) {
        float a = al[nl][k];
        float4 w = Wl[k][c4];
        o.x = fmaf(a, w.x, o.x);
        o.y = fmaf(a, w.y, o.y);
        o.z = fmaf(a, w.z, o.z);
        o.w = fmaf(a, w.w, o.w);
    }
    o.x = fmaxf(o.x, 0.f); o.y = fmaxf(o.y, 0.f);
    o.z = fmaxf(o.z, 0.f); o.w = fmaxf(o.w, 0.f);
    if (!LAST) { o.x *= dv; o.y *= dv; o.z *= dv; o.w *= dv; }
    ((float4*)out)[(size_t)node * 16 + c4] = o;
}

// ---------------------------------------------------------------------------
__global__ void k_bounds(const int* __restrict__ batch, int* __restrict__ gstart) {
    int i = blockIdx.x * 256 + threadIdx.x;
    if (i >= NN) return;
    int b = batch[i];
    if (i == 0) {
        for (int g = 0; g <= b; ++g) gstart[g] = 0;
    } else {
        int bp = batch[i - 1];
        for (int g = bp + 1; g <= b; ++g) gstart[g] = i;
    }
    if (i == NN - 1) {
        for (int g = b + 1; g <= NG; ++g) gstart[g] = NN;
    }
}

__global__ void k_pool(const float* __restrict__ h, const int* __restrict__ gstart,
                       float* __restrict__ out) {
    __shared__ float s[4][64];
    int g = blockIdx.x;
    int t = threadIdx.x, lane = t & 63, w = t >> 6;
    int r0 = gstart[g], r1 = gstart[g + 1];
    float acc = 0.f;
    for (int r = r0 + w; r < r1; r += 4) acc += h[(size_t)r * 64 + lane];
    s[w][lane] = acc;
    __syncthreads();
    if (t < 64) {
        float v = s[0][t] + s[1][t] + s[2][t] + s[3][t];
        float c = (float)(r1 - r0);
        out[g * 64 + t] = v / fmaxf(c, 1.f);
    }
}

// ---------------------------------------------------------------------------
static inline size_t al256(size_t x) { return (x + 255) & ~(size_t)255; }

extern "C" void kernel_launch(void* const* d_in, const int* in_sizes, int n_in,
                              void* d_out, int out_size, void* d_ws, size_t ws_size,
                              hipStream_t stream) {
    const float* x     = (const float*)d_in[0];
    const int*   eidx  = (const int*)d_in[1];
    const int*   batch = (const int*)d_in[2];
    const float* W1 = (const float*)d_in[3];  const float* b1 = (const float*)d_in[4];
    const float* W2 = (const float*)d_in[5];  const float* b2 = (const float*)d_in[6];
    const float* W3 = (const float*)d_in[7];  const float* b3 = (const float*)d_in[8];
    const float* W4 = (const float*)d_in[9];  const float* b4 = (const float*)d_in[10];
    float* out = (float*)d_out;
    (void)in_sizes; (void)n_in; (void)out_size; (void)ws_size;

    const int* src = eidx;
    const int* dst = eidx + NE;

    char* p = (char*)d_ws;
    size_t off = 0;
    int*   bcount  = (int*)(p + off);   off = al256(off + sizeof(int) * NB);
    int*   bbase   = (int*)(p + off);   off = al256(off + sizeof(int) * (NB + 1));
    int*   gcur    = (int*)(p + off);   off = al256(off + sizeof(int) * NB);
    int*   gstart  = (int*)(p + off);   off = al256(off + sizeof(int) * (NG + 1));
    int*   row_off = (int*)(p + off);   off = al256(off + sizeof(int) * (NN + 1));
    float* dinv    = (float*)(p + off); off = al256(off + sizeof(float) * NN);
    int*   csr     = (int*)(p + off);   off = al256(off + sizeof(int) * NE);
    float* F0      = (float*)(p + off); off = al256(off + sizeof(float) * (size_t)NN * 64);
    float* F1      = (float*)(p + off); off = al256(off + sizeof(float) * (size_t)NN * 64);
    unsigned* barray = (unsigned*)F0;   // dead before fused1 writes F0
    float*    xs     = F1;              // dead before layer-2 writes F1

    hipMemsetAsync(bcount, 0, sizeof(int) * NB, stream);

    ph0_hist     <<<256, 256, 0, stream>>>(dst, bcount);
    ph_scan      <<<1, NB, 0, stream>>>(bcount, bbase, gcur, row_off);
    ph1_bucketize<<<256, 256, 0, stream>>>(src, dst, gcur, barray);
    ph2_build    <<<NB, 256, 0, stream>>>(barray, bbase, row_off, dinv, csr);
    k_pad        <<<(NN * 16 + 255) / 256, 256, 0, stream>>>(x, dinv, xs);

    fused1       <<<(NN + 63) / 64, 256, 0, stream>>>(xs, row_off, csr, dinv, W1, b1, F0);
    fused64<false><<<(NN + 15) / 16, 256, 0, stream>>>(F0, row_off, csr, dinv, W2, b2, F1);
    fused64<false><<<(NN + 15) / 16, 256, 0, stream>>>(F1, row_off, csr, dinv, W3, b3, F0);
    fused64<true> <<<(NN + 15) / 16, 256, 0, stream>>>(F0, row_off, csr, dinv, W4, b4, F1);

    k_bounds<<<NBLK, 256, 0, stream>>>(batch, gstart);
    k_pool  <<<NG, 256, 0, stream>>>(F1, gstart, out);
}

// Round 4
// 233.496 us; speedup vs baseline: 4.9527x; 1.2629x over previous
//
#include <hip/hip_runtime.h>
#include <hip/hip_bf16.h>

#define NN 100000
#define NE 1200000
#define NG 256
#define NB 256          // dst buckets
#define BSZ 391         // nodes per bucket (ceil(NN/NB))
#define ECHUNK 4688     // edges per bucketize block (ceil(NE/256))
#define MAXB 6144       // max edges per bucket (mean 4692)
#define NBLK 391        // ceil(NN/256)

// bf16 helpers (RNE)
__device__ __forceinline__ unsigned f2b(float f) {
    unsigned b = __float_as_uint(f);
    return (b + 0x7FFFu + ((b >> 16) & 1u)) >> 16;
}
__device__ __forceinline__ float b2f(unsigned short u) {
    return __uint_as_float((unsigned)u << 16);
}
__device__ __forceinline__ float4 b2f4(ushort4 u) {
    return make_float4(b2f(u.x), b2f(u.y), b2f(u.z), b2f(u.w));
}

// ---------------------------------------------------------------------------
__global__ void ph0_hist(const int* __restrict__ dst, int* __restrict__ bcount) {
    __shared__ int h[NB];
    const int t = threadIdx.x;
    h[t] = 0;
    __syncthreads();
    const int e0 = blockIdx.x * ECHUNK;
    const int cnt = min(ECHUNK, NE - e0);
    for (int i = t; i < cnt; i += 256)
        atomicAdd(&h[dst[e0 + i] / BSZ], 1);
    __syncthreads();
    atomicAdd(&bcount[t], h[t]);
}

__global__ void ph_scan(const int* __restrict__ bcount, int* __restrict__ bbase,
                        int* __restrict__ gcur, int* __restrict__ row_off) {
    __shared__ int s[NB];
    const int t = threadIdx.x;
    int v = bcount[t];
    s[t] = v;
    __syncthreads();
    for (int off = 1; off < NB; off <<= 1) {
        int u = (t >= off) ? s[t - off] : 0;
        __syncthreads();
        s[t] += u;
        __syncthreads();
    }
    int base = s[t] - v;
    bbase[t] = base;
    gcur[t] = base;
    if (t == NB - 1) { bbase[NB] = s[t]; row_off[NN] = NE; }
}

__global__ void ph1_bucketize(const int* __restrict__ src, const int* __restrict__ dst,
                              int* __restrict__ gcur, unsigned* __restrict__ barray) {
    __shared__ int ldst[ECHUNK];
    __shared__ int lsrc[ECHUNK];
    __shared__ int hist[NB];
    __shared__ int lbase[NB];
    __shared__ int lcur[NB];
    const int t = threadIdx.x;
    const int e0 = blockIdx.x * ECHUNK;
    const int cnt = min(ECHUNK, NE - e0);
    hist[t] = 0;
    __syncthreads();
    for (int i = t; i < cnt; i += 256) {
        int d = dst[e0 + i], s = src[e0 + i];
        ldst[i] = d; lsrc[i] = s;
        atomicAdd(&hist[d / BSZ], 1);
    }
    __syncthreads();
    lbase[t] = atomicAdd(&gcur[t], hist[t]);
    lcur[t] = 0;
    __syncthreads();
    for (int i = t; i < cnt; i += 256) {
        int d = ldst[i];
        int b = d / BSZ;
        int pos = lbase[b] + atomicAdd(&lcur[b], 1);
        barray[pos] = ((unsigned)(d - b * BSZ) << 17) | (unsigned)lsrc[i];
    }
}

__global__ void ph2_build(const unsigned* __restrict__ barray, const int* __restrict__ bbase,
                          int* __restrict__ row_off, float* __restrict__ dinv,
                          int* __restrict__ csr) {
    __shared__ unsigned estage[MAXB];
    __shared__ int lcsr[MAXB];
    __shared__ int s[512];
    __shared__ int cur[BSZ];
    const int t = threadIdx.x;
    const int b = blockIdx.x;
    const int ebase = bbase[b];
    const int cnt = bbase[b + 1] - ebase;
    const int nbase = b * BSZ;
    const int nnodes = min(BSZ, NN - nbase);
    s[t] = 0; s[t + 256] = 0;
    __syncthreads();
    for (int i = t; i < cnt; i += 256) {
        unsigned e = barray[ebase + i];
        estage[i] = e;
        atomicAdd(&s[e >> 17], 1);
    }
    __syncthreads();
    for (int off = 1; off < 512; off <<= 1) {
        int v1 = (t >= off) ? s[t - off] : 0;
        int v2 = s[t + 256 - off];
        __syncthreads();
        s[t] += v1; s[t + 256] += v2;
        __syncthreads();
    }
    for (int l = t; l < nnodes; l += 256) {
        int incl = s[l];
        int excl = l ? s[l - 1] : 0;
        row_off[nbase + l] = ebase + excl;
        dinv[nbase + l] = rsqrtf((float)(incl - excl) + 1.0f);
        cur[l] = excl;
    }
    __syncthreads();
    for (int i = t; i < cnt; i += 256) {
        unsigned e = estage[i];
        int pos = atomicAdd(&cur[e >> 17], 1);
        lcsr[pos] = (int)(e & 0x1FFFFu);
    }
    __syncthreads();
    for (int i = t; i < cnt; i += 256)
        csr[ebase + i] = lcsr[i];
}

// ---------------------------------------------------------------------------
// xs[n][k] = bf16(dinv[n]*x[n][k]) (k<15), 0 at k==15 (pad to 16)
__global__ void k_pad(const float* __restrict__ x, const float* __restrict__ dinv,
                      unsigned short* __restrict__ xs) {
    int i = blockIdx.x * 256 + threadIdx.x;
    if (i < NN * 16) {
        int n = i >> 4, k = i & 15;
        float v = (k < 15) ? dinv[n] * x[n * 15 + k] : 0.f;
        xs[i] = (unsigned short)f2b(v);
    }
}

// ---------------------------------------------------------------------------
// Layer 1: 16-d bf16 gather -> 16x64 matmul -> bf16 out. 64 nodes/block.
__global__ void fused1(const unsigned short* __restrict__ xs, const int* __restrict__ row_off,
                       const int* __restrict__ csr, const float* __restrict__ dinv,
                       const float* __restrict__ W, const float* __restrict__ bias,
                       unsigned* __restrict__ out) {
    __shared__ float4 Wl[16][16];
    __shared__ float  al[64][20];
    const int t = threadIdx.x;
    if (t < 240) Wl[t >> 4][t & 15] = ((const float4*)W)[t];
    if (t < 16) Wl[15][t] = make_float4(0,0,0,0);
    const int nl = t >> 2, c4 = t & 3;
    const int node = blockIdx.x * 64 + nl;
    float4 acc = make_float4(0,0,0,0);
    float dv = 0.f;
    if (node < NN) {
        const ushort4* base = (const ushort4*)xs;   // row = 4 x ushort4
        acc = b2f4(base[(size_t)node * 4 + c4]);    // self-loop
        int p = row_off[node], e = row_off[node + 1];
        for (; p + 3 < e; p += 4) {
            int s0 = csr[p], s1 = csr[p+1], s2 = csr[p+2], s3 = csr[p+3];
            float4 a = b2f4(base[(size_t)s0 * 4 + c4]);
            float4 b = b2f4(base[(size_t)s1 * 4 + c4]);
            float4 c = b2f4(base[(size_t)s2 * 4 + c4]);
            float4 d = b2f4(base[(size_t)s3 * 4 + c4]);
            acc.x += (a.x + b.x) + (c.x + d.x);
            acc.y += (a.y + b.y) + (c.y + d.y);
            acc.z += (a.z + b.z) + (c.z + d.z);
            acc.w += (a.w + b.w) + (c.w + d.w);
        }
        for (; p < e; ++p) {
            float4 a = b2f4(base[(size_t)csr[p] * 4 + c4]);
            acc.x += a.x; acc.y += a.y; acc.z += a.z; acc.w += a.w;
        }
        dv = dinv[node];
        acc.x *= dv; acc.y *= dv; acc.z *= dv; acc.w *= dv;
    }
    ((float4*)&al[nl][0])[c4] = acc;
    __syncthreads();
    if (node >= NN) return;
    float4 o0 = ((const float4*)bias)[c4 * 4 + 0];
    float4 o1 = ((const float4*)bias)[c4 * 4 + 1];
    float4 o2 = ((const float4*)bias)[c4 * 4 + 2];
    float4 o3 = ((const float4*)bias)[c4 * 4 + 3];
#pragma unroll
    for (int k = 0; k < 16; ++k) {
        float a = al[nl][k];
        float4 w0 = Wl[k][c4 * 4 + 0];
        float4 w1 = Wl[k][c4 * 4 + 1];
        float4 w2 = Wl[k][c4 * 4 + 2];
        float4 w3 = Wl[k][c4 * 4 + 3];
        o0.x = fmaf(a, w0.x, o0.x); o0.y = fmaf(a, w0.y, o0.y); o0.z = fmaf(a, w0.z, o0.z); o0.w = fmaf(a, w0.w, o0.w);
        o1.x = fmaf(a, w1.x, o1.x); o1.y = fmaf(a, w1.y, o1.y); o1.z = fmaf(a, w1.z, o1.z); o1.w = fmaf(a, w1.w, o1.w);
        o2.x = fmaf(a, w2.x, o2.x); o2.y = fmaf(a, w2.y, o2.y); o2.z = fmaf(a, w2.z, o2.z); o2.w = fmaf(a, w2.w, o2.w);
        o3.x = fmaf(a, w3.x, o3.x); o3.y = fmaf(a, w3.y, o3.y); o3.z = fmaf(a, w3.z, o3.z); o3.w = fmaf(a, w3.w, o3.w);
    }
    float dv2 = dv;
    o0.x = fmaxf(o0.x, 0.f) * dv2; o0.y = fmaxf(o0.y, 0.f) * dv2; o0.z = fmaxf(o0.z, 0.f) * dv2; o0.w = fmaxf(o0.w, 0.f) * dv2;
    o1.x = fmaxf(o1.x, 0.f) * dv2; o1.y = fmaxf(o1.y, 0.f) * dv2; o1.z = fmaxf(o1.z, 0.f) * dv2; o1.w = fmaxf(o1.w, 0.f) * dv2;
    o2.x = fmaxf(o2.x, 0.f) * dv2; o2.y = fmaxf(o2.y, 0.f) * dv2; o2.z = fmaxf(o2.z, 0.f) * dv2; o2.w = fmaxf(o2.w, 0.f) * dv2;
    o3.x = fmaxf(o3.x, 0.f) * dv2; o3.y = fmaxf(o3.y, 0.f) * dv2; o3.z = fmaxf(o3.z, 0.f) * dv2; o3.w = fmaxf(o3.w, 0.f) * dv2;
    uint4 lo, hi;
    lo.x = f2b(o0.x) | (f2b(o0.y) << 16);
    lo.y = f2b(o0.z) | (f2b(o0.w) << 16);
    lo.z = f2b(o1.x) | (f2b(o1.y) << 16);
    lo.w = f2b(o1.z) | (f2b(o1.w) << 16);
    hi.x = f2b(o2.x) | (f2b(o2.y) << 16);
    hi.y = f2b(o2.z) | (f2b(o2.w) << 16);
    hi.z = f2b(o3.x) | (f2b(o3.y) << 16);
    hi.w = f2b(o3.z) | (f2b(o3.w) << 16);
    uint4* ob = (uint4*)out + (size_t)node * 8 + c4 * 2;   // row = 8 x uint4 (128 B)
    ob[0] = lo; ob[1] = hi;
}

// ---------------------------------------------------------------------------
// Layers 2..4: 64-d bf16 gather -> 64x64 matmul. LAST writes f32, else bf16.
template <bool LAST>
__global__ void fused64(const unsigned short* __restrict__ g, const int* __restrict__ row_off,
                        const int* __restrict__ csr, const float* __restrict__ dinv,
                        const float* __restrict__ W, const float* __restrict__ bias,
                        void* __restrict__ outv) {
    __shared__ float4 Wl[64][16];
    __shared__ float  al[16][68];
    const int t = threadIdx.x;
    for (int i = t; i < 1024; i += 256)
        Wl[i >> 4][i & 15] = ((const float4*)W)[i];
    const int nl = t >> 4, c4 = t & 15;
    const int node = blockIdx.x * 16 + nl;
    float4 acc = make_float4(0,0,0,0);
    float dv = 0.f;
    if (node < NN) {
        const ushort4* base = (const ushort4*)g;    // row = 16 x ushort4 (128 B)
        acc = b2f4(base[(size_t)node * 16 + c4]);   // self-loop
        int p = row_off[node], e = row_off[node + 1];
        for (; p + 3 < e; p += 4) {
            int s0 = csr[p], s1 = csr[p+1], s2 = csr[p+2], s3 = csr[p+3];
            float4 a = b2f4(base[(size_t)s0 * 16 + c4]);
            float4 b = b2f4(base[(size_t)s1 * 16 + c4]);
            float4 c = b2f4(base[(size_t)s2 * 16 + c4]);
            float4 d = b2f4(base[(size_t)s3 * 16 + c4]);
            acc.x += (a.x + b.x) + (c.x + d.x);
            acc.y += (a.y + b.y) + (c.y + d.y);
            acc.z += (a.z + b.z) + (c.z + d.z);
            acc.w += (a.w + b.w) + (c.w + d.w);
        }
        for (; p < e; ++p) {
            float4 a = b2f4(base[(size_t)csr[p] * 16 + c4]);
            acc.x += a.x; acc.y += a.y; acc.z += a.z; acc.w += a.w;
        }
        dv = dinv[node];
        acc.x *= dv; acc.y *= dv; acc.z *= dv; acc.w *= dv;
    }
    ((float4*)&al[nl][0])[c4] = acc;
    __syncthreads();
    if (node >= NN) return;
    float4 o = ((const float4*)bias)[c4];
#pragma unroll
    for (int k = 0; k < 64; ++k) {
        float a = al[nl][k];
        float4 w = Wl[k][c4];
        o.x = fmaf(a, w.x, o.x);
        o.y = fmaf(a, w.y, o.y);
        o.z = fmaf(a, w.z, o.z);
        o.w = fmaf(a, w.w, o.w);
    }
    o.x = fmaxf(o.x, 0.f); o.y = fmaxf(o.y, 0.f);
    o.z = fmaxf(o.z, 0.f); o.w = fmaxf(o.w, 0.f);
    if (!LAST) {
        o.x *= dv; o.y *= dv; o.z *= dv; o.w *= dv;
        ushort4 uo;
        uo.x = (unsigned short)f2b(o.x);
        uo.y = (unsigned short)f2b(o.y);
        uo.z = (unsigned short)f2b(o.z);
        uo.w = (unsigned short)f2b(o.w);
        ((ushort4*)outv)[(size_t)node * 16 + c4] = uo;
    } else {
        ((float4*)outv)[(size_t)node * 16 + c4] = o;
    }
}

// ---------------------------------------------------------------------------
__global__ void k_bounds(const int* __restrict__ batch, int* __restrict__ gstart) {
    int i = blockIdx.x * 256 + threadIdx.x;
    if (i >= NN) return;
    int b = batch[i];
    if (i == 0) {
        for (int g = 0; g <= b; ++g) gstart[g] = 0;
    } else {
        int bp = batch[i - 1];
        for (int g = bp + 1; g <= b; ++g) gstart[g] = i;
    }
    if (i == NN - 1) {
        for (int g = b + 1; g <= NG; ++g) gstart[g] = NN;
    }
}

__global__ void k_pool(const float* __restrict__ h, const int* __restrict__ gstart,
                       float* __restrict__ out) {
    __shared__ float s[4][64];
    int g = blockIdx.x;
    int t = threadIdx.x, lane = t & 63, w = t >> 6;
    int r0 = gstart[g], r1 = gstart[g + 1];
    float acc = 0.f;
    for (int r = r0 + w; r < r1; r += 4) acc += h[(size_t)r * 64 + lane];
    s[w][lane] = acc;
    __syncthreads();
    if (t < 64) {
        float v = s[0][t] + s[1][t] + s[2][t] + s[3][t];
        float c = (float)(r1 - r0);
        out[g * 64 + t] = v / fmaxf(c, 1.f);
    }
}

// ---------------------------------------------------------------------------
static inline size_t al256(size_t x) { return (x + 255) & ~(size_t)255; }

extern "C" void kernel_launch(void* const* d_in, const int* in_sizes, int n_in,
                              void* d_out, int out_size, void* d_ws, size_t ws_size,
                              hipStream_t stream) {
    const float* x     = (const float*)d_in[0];
    const int*   eidx  = (const int*)d_in[1];
    const int*   batch = (const int*)d_in[2];
    const float* W1 = (const float*)d_in[3];  const float* b1 = (const float*)d_in[4];
    const float* W2 = (const float*)d_in[5];  const float* b2 = (const float*)d_in[6];
    const float* W3 = (const float*)d_in[7];  const float* b3 = (const float*)d_in[8];
    const float* W4 = (const float*)d_in[9];  const float* b4 = (const float*)d_in[10];
    float* out = (float*)d_out;
    (void)in_sizes; (void)n_in; (void)out_size; (void)ws_size;

    const int* src = eidx;
    const int* dst = eidx + NE;

    char* p = (char*)d_ws;
    size_t off = 0;
    int*   bcount  = (int*)(p + off);   off = al256(off + sizeof(int) * NB);
    int*   bbase   = (int*)(p + off);   off = al256(off + sizeof(int) * (NB + 1));
    int*   gcur    = (int*)(p + off);   off = al256(off + sizeof(int) * NB);
    int*   gstart  = (int*)(p + off);   off = al256(off + sizeof(int) * (NG + 1));
    int*   row_off = (int*)(p + off);   off = al256(off + sizeof(int) * (NN + 1));
    float* dinv    = (float*)(p + off); off = al256(off + sizeof(float) * NN);
    int*   csr     = (int*)(p + off);   off = al256(off + sizeof(int) * NE);
    unsigned short* F0 = (unsigned short*)(p + off); off = al256(off + sizeof(short) * (size_t)NN * 64);
    unsigned short* F1 = (unsigned short*)(p + off); off = al256(off + sizeof(short) * (size_t)NN * 64);
    float* H4      = (float*)(p + off); off = al256(off + sizeof(float) * (size_t)NN * 64);
    unsigned*       barray = (unsigned*)H4;        // dead before layer-4 writes H4
    unsigned short* xs     = F1;                   // dead before layer-2 writes F1

    hipMemsetAsync(bcount, 0, sizeof(int) * NB, stream);

    ph0_hist     <<<256, 256, 0, stream>>>(dst, bcount);
    ph_scan      <<<1, NB, 0, stream>>>(bcount, bbase, gcur, row_off);
    ph1_bucketize<<<256, 256, 0, stream>>>(src, dst, gcur, barray);
    ph2_build    <<<NB, 256, 0, stream>>>(barray, bbase, row_off, dinv, csr);
    k_pad        <<<(NN * 16 + 255) / 256, 256, 0, stream>>>(x, dinv, xs);

    fused1        <<<(NN + 63) / 64, 256, 0, stream>>>(xs, row_off, csr, dinv, W1, b1, (unsigned*)F0);
    fused64<false><<<(NN + 15) / 16, 256, 0, stream>>>(F0, row_off, csr, dinv, W2, b2, F1);
    fused64<false><<<(NN + 15) / 16, 256, 0, stream>>>(F1, row_off, csr, dinv, W3, b3, F0);
    fused64<true> <<<(NN + 15) / 16, 256, 0, stream>>>(F0, row_off, csr, dinv, W4, b4, H4);

    k_bounds<<<NBLK, 256, 0, stream>>>(batch, gstart);
    k_pool  <<<NG, 256, 0, stream>>>(H4, gstart, out);
}